// Round 4
// baseline (362.229 us; speedup 1.0000x reference)
//
#include <hip/hip_runtime.h>
#include <hip/hip_bf16.h>

// TreeRNN: K=8, DEPTH=7, N=299593, V=32000, X=H=O=128.
// bf16 MFMA 16x16x32, fp32 accumulate. Round-4 structure:
//  - GEMM1 A-fragments gathered DIRECTLY from emb into registers (MFMA A
//    layout m=lane&15, k=(lane>>4)*8+j == 8 contiguous floats per lane) —
//    no LDS round trip for phase 1.
//  - Leaf kernel: 2048 blocks x 2 tiles, software-pipelined (tile1 gather
//    issued before tile0 compute body).
//  - No bounds checks on exact levels (leaf, l=5,4,3 are exact x64 tiles).
//  - LDS used only for the C-layout -> A-layout transpose of h (GEMM2) and
//    the child-sum staging at non-leaf levels. All wave-private, no
//    __syncthreads in level path.

typedef __bf16 bf16x8 __attribute__((ext_vector_type(8)));
typedef float f32x4 __attribute__((ext_vector_type(4)));
typedef float f32x2 __attribute__((ext_vector_type(2)));
typedef unsigned short ushort8 __attribute__((ext_vector_type(8)));

#define NNODES 299593

static __device__ __forceinline__ unsigned short f2bf(float f) {
  union { float f; unsigned int u; } v; v.f = f;
  unsigned int u = v.u;
  u += 0x7fff + ((u >> 16) & 1);   // RNE
  return (unsigned short)(u >> 16);
}

static __device__ __forceinline__ unsigned int pk2bf(float a, float b) {
#if __has_builtin(__builtin_amdgcn_cvt_pk_bf16_f32)
  typedef __bf16 bf16x2 __attribute__((ext_vector_type(2)));
  union { bf16x2 v; unsigned int u; } c;
  c.v = __builtin_amdgcn_cvt_pk_bf16_f32(a, b);
  return c.u;
#else
  return (unsigned int)f2bf(a) | ((unsigned int)f2bf(b) << 16);
#endif
}

// tanh(x) = 1 - 2/(1+e^{2x})
static __device__ __forceinline__ float fast_tanh(float x) {
  float y = x * 2.885390081777927f;  // 2*log2(e)
#if __has_builtin(__builtin_amdgcn_exp2f)
  float e = __builtin_amdgcn_exp2f(y);
#else
  float e = __builtin_exp2f(y);
#endif
#if __has_builtin(__builtin_amdgcn_rcpf)
  float r = __builtin_amdgcn_rcpf(e + 1.0f);
#else
  float r = 1.0f / (e + 1.0f);
#endif
  return __builtin_fmaf(-2.0f, r, 1.0f);
}

// Swizzle W (128x128 row-major fp32) into B-fragment order for
// v_mfma_f32_16x16x32_bf16: frag f = ((kt*8+nt)*64 + lane)*8 + j
// holds W[kt*32 + (lane>>4)*8 + j][nt*16 + (lane&15)].
__global__ void prep_weights(const float* __restrict__ W_in,
                             const float* __restrict__ U,
                             const float* __restrict__ W_out,
                             unsigned short* __restrict__ w_sw) {
  int f = blockIdx.x * 256 + threadIdx.x;   // 0..49151
  int m = f >> 14;
  int r = f & 16383;
  int j = r & 7;
  int lane = (r >> 3) & 63;
  int nt = (r >> 9) & 7;
  int kt = (r >> 12) & 3;
  int k = kt * 32 + ((lane >> 4) * 8) + j;
  int n = nt * 16 + (lane & 15);
  const float* W = (m == 0) ? W_in : (m == 1) ? U : W_out;
  w_sw[f] = f2bf(W[k * 128 + n]);
}

union U8 { ushort8 s; bf16x8 v; unsigned int u[4]; };

struct Raw { f32x4 p[8]; float fm; };

// Issue the emb gather for this lane's A-fragment chunk (8 floats per kt).
static __device__ __forceinline__ void gather_issue(Raw& r, const int* x,
    const int* mask, const float* emb, int row, int valid, int quad) {
  int m = 0, idx = 0;
  if (valid) { m = mask[row]; idx = x[row] * m; }
  r.fm = (float)m;
  const float* er = emb + (size_t)idx * 128 + quad * 8;
#pragma unroll
  for (int kt = 0; kt < 4; ++kt) {
    r.p[kt * 2]     = *(const f32x4*)(er + kt * 32);
    r.p[kt * 2 + 1] = *(const f32x4*)(er + kt * 32 + 4);
  }
}

static __device__ __forceinline__ void cvt_af(bf16x8 af[4], const Raw& r) {
  const float fm = r.fm;
#pragma unroll
  for (int kt = 0; kt < 4; ++kt) {
    U8 w;
    f32x4 a = r.p[kt * 2], b = r.p[kt * 2 + 1];
    w.u[0] = pk2bf(a[0] * fm, a[1] * fm);
    w.u[1] = pk2bf(a[2] * fm, a[3] * fm);
    w.u[2] = pk2bf(b[0] * fm, b[1] * fm);
    w.u[3] = pk2bf(b[2] * fm, b[3] * fm);
    af[kt] = w.v;
  }
}

// GEMM with A from registers, B from pre-swizzled global (L1/L2-resident).
static __device__ __forceinline__ void gemm_reg(f32x4 acc[8],
    const bf16x8 af[4], const unsigned short* b_sw, int lane) {
#pragma unroll
  for (int kt = 0; kt < 4; ++kt)
#pragma unroll
    for (int nt = 0; nt < 8; ++nt) {
      bf16x8 b = *(const bf16x8*)(b_sw + (((kt * 8 + nt) * 64 + lane) * 8));
      acc[nt] = __builtin_amdgcn_mfma_f32_16x16x32_bf16(af[kt], b, acc[nt],
                                                        0, 0, 0);
    }
}

// GEMM with A from wave-private LDS region (row stride 136 ushorts).
static __device__ __forceinline__ void gemm_lds(f32x4 acc[8],
    const unsigned short* a_base, const unsigned short* b_sw, int lane) {
  const int coll = lane & 15;
  const int quad = lane >> 4;
#pragma unroll
  for (int kt = 0; kt < 4; ++kt) {
    bf16x8 a = *(const bf16x8*)(a_base + coll * 136 + kt * 32 + quad * 8);
#pragma unroll
    for (int nt = 0; nt < 8; ++nt) {
      bf16x8 b = *(const bf16x8*)(b_sw + (((kt * 8 + nt) * 64 + lane) * 8));
      acc[nt] = __builtin_amdgcn_mfma_f32_16x16x32_bf16(a, b, acc[nt], 0, 0, 0);
    }
  }
}

// Core: takes converted A-frags for GEMM1; does (optional) child-sum + U GEMM,
// tanh, h store, out GEMM + store. Aw = wave-private 16-row LDS region.
template <bool LEAF, bool BOUNDS>
static __device__ __forceinline__ void tile_core(
    const bf16x8 af[4], float fm, int row0w, int e, const unsigned short* w_sw,
    unsigned short* __restrict__ h, float* __restrict__ out,
    unsigned short (*Aw)[136], int lane, const float* binv,
    const float* boutv) {
  const int coll = lane & 15;
  const int quad = lane >> 4;

  f32x4 acc[8];
#pragma unroll
  for (int nt = 0; nt < 8; ++nt) acc[nt] = (f32x4){0.f, 0.f, 0.f, 0.f};
  gemm_reg(acc, af, w_sw, lane);                          // emb @ W_in

  if (!LEAF) {
    // child-sum of 8 contiguous h rows -> LDS (cooperative, wave-private)
    const int r = lane >> 2;        // 0..15
    const int cg = lane & 3;        // 32-col group
    const int grow = row0w + r;
    f32x2 sums[16];
#pragma unroll
    for (int q = 0; q < 16; ++q) sums[q] = (f32x2){0.f, 0.f};
    if (!BOUNDS || grow < e) {
      const unsigned short* hp = h + ((size_t)grow * 8 + 1) * 128 + cg * 32;
#pragma unroll
      for (int j = 0; j < 8; ++j) {
#pragma unroll
        for (int b = 0; b < 2; ++b) {
          U8 hv;
          hv.s = *(const ushort8*)(hp + j * 128 + b * 16);
#pragma unroll
          for (int q = 0; q < 4; ++q) {
            union { unsigned int u; float f; } lo, hi;
            lo.u = hv.u[q] << 16;
            hi.u = hv.u[q] & 0xffff0000u;
            sums[b * 8 + q] += (f32x2){lo.f, hi.f};
          }
          hv.s = *(const ushort8*)(hp + j * 128 + b * 16 + 8);
#pragma unroll
          for (int q = 0; q < 4; ++q) {
            union { unsigned int u; float f; } lo, hi;
            lo.u = hv.u[q] << 16;
            hi.u = hv.u[q] & 0xffff0000u;
            sums[b * 8 + 4 + q] += (f32x2){lo.f, hi.f};
          }
        }
      }
    }
    // sums[b*8+q] = cols cg*32 + b*16 + (2q, 2q+1)
#pragma unroll
    for (int b = 0; b < 2; ++b) {
      U8 w0, w1;
#pragma unroll
      for (int q = 0; q < 4; ++q) {
        w0.u[q] = pk2bf(sums[b * 8 + q][0], sums[b * 8 + q][1]);
        w1.u[q] = pk2bf(sums[b * 8 + 4 + q][0], sums[b * 8 + 4 + q][1]);
      }
      *(ushort8*)&Aw[r][cg * 32 + b * 16] = w0.s;
      *(ushort8*)&Aw[r][cg * 32 + b * 16 + 8] = w1.s;
    }
    __builtin_amdgcn_wave_barrier();
    gemm_lds(acc, &Aw[0][0], w_sw + 16384, lane);         // (sum ch) @ U
    __builtin_amdgcn_wave_barrier();
  }

  // epilogue: + m*b_in, tanh; write h into LDS in C layout (for transpose).
  // mask of row (quad*4+r2) fetched by shfl from lane (quad*4+r2) (coll==lane
  // for lanes 0..15).
#pragma unroll
  for (int r2 = 0; r2 < 4; ++r2) {
    const int rowl = quad * 4 + r2;
    const float mval = __shfl(fm, rowl);
#pragma unroll
    for (int nt = 0; nt < 8; ++nt) {
      float t = acc[nt][r2] + mval * binv[nt];
      Aw[rowl][nt * 16 + coll] = f2bf(fast_tanh(t));
    }
  }
  __builtin_amdgcn_wave_barrier();

  // h store (bf16) vectorized from LDS
  {
    const int sr = lane >> 2;
    const int sc = (lane & 3) * 8;
    const int grow = row0w + sr;
    if (!BOUNDS || grow < e) {
      unsigned short* hp = h + (size_t)grow * 128;
#pragma unroll
      for (int i = 0; i < 4; ++i)
        *(ushort8*)(hp + sc + i * 32) = *(const ushort8*)&Aw[sr][sc + i * 32];
    }
  }

  // out = h @ W_out + b_out (reuse acc registers)
#pragma unroll
  for (int nt = 0; nt < 8; ++nt) acc[nt] = (f32x4){0.f, 0.f, 0.f, 0.f};
  gemm_lds(acc, &Aw[0][0], w_sw + 32768, lane);

#pragma unroll
  for (int r2 = 0; r2 < 4; ++r2) {
    const int grow = row0w + quad * 4 + r2;
    if (!BOUNDS || grow < e) {
#pragma unroll
      for (int nt = 0; nt < 8; ++nt)
        out[(size_t)grow * 128 + nt * 16 + coll] = acc[nt][r2] + boutv[nt];
    }
  }
}

// Non-leaf level tile (gather + core), shared by level_kernel and tail.
template <bool BOUNDS>
static __device__ __forceinline__ void level_body(
    const int* __restrict__ x, const int* __restrict__ mask,
    const float* __restrict__ emb, const unsigned short* __restrict__ w_sw,
    unsigned short* __restrict__ h, float* __restrict__ out, int row0blk,
    int e, unsigned short (*Abuf)[136], int tid, const float* binv,
    const float* boutv) {
  const int lane = tid & 63;
  const int wave = tid >> 6;
  const int quad = lane >> 4;
  const int row0w = row0blk + wave * 16;
  const int row = row0w + (lane & 15);
  Raw ra;
  gather_issue(ra, x, mask, emb, row, !BOUNDS || row < e, quad);
  bf16x8 af[4];
  cvt_af(af, ra);
  tile_core<false, BOUNDS>(af, ra.fm, row0w, e, w_sw, h, out,
                           (unsigned short(*)[136]) & Abuf[wave * 16], lane,
                           binv, boutv);
}

// Leaf: 2 tiles per block, pipelined (tile1 gather issued before tile0 body).
__global__ __launch_bounds__(256) void leaf_kernel(
    const int* __restrict__ x, const int* __restrict__ mask,
    const float* __restrict__ emb, const float* __restrict__ b_in,
    const float* __restrict__ b_out, const unsigned short* __restrict__ w_sw,
    unsigned short* __restrict__ h, float* __restrict__ out) {
  __shared__ __align__(16) unsigned short Abuf[64][136];
  const int tid = threadIdx.x;
  const int lane = tid & 63;
  const int wave = tid >> 6;
  const int coll = lane & 15;
  const int quad = lane >> 4;
  unsigned short(*Aw)[136] = (unsigned short(*)[136]) & Abuf[wave * 16];

  float binv[8], boutv[8];
#pragma unroll
  for (int nt = 0; nt < 8; ++nt) {
    binv[nt] = b_in[nt * 16 + coll];
    boutv[nt] = b_out[nt * 16 + coll];
  }

  const int r0w = 37449 + blockIdx.x * 64 + wave * 16;
  const int r1w = r0w + 2048 * 64;

  Raw ra;
  gather_issue(ra, x, mask, emb, r0w + coll, 1, quad);
  bf16x8 af[4];
  cvt_af(af, ra);                      // waits on tile0 gather
  Raw rb;
  gather_issue(rb, x, mask, emb, r1w + coll, 1, quad);  // in flight over tile0
  tile_core<true, false>(af, ra.fm, r0w, 0, w_sw, h, out, Aw, lane, binv,
                         boutv);
  cvt_af(af, rb);
  tile_core<true, false>(af, rb.fm, r1w, 0, w_sw, h, out, Aw, lane, binv,
                         boutv);
}

template <bool BOUNDS>
__global__ __launch_bounds__(256) void level_kernel(
    const int* __restrict__ x, const int* __restrict__ mask,
    const float* __restrict__ emb, const float* __restrict__ b_in,
    const float* __restrict__ b_out, const unsigned short* __restrict__ w_sw,
    unsigned short* __restrict__ h, float* __restrict__ out, int s, int e) {
  __shared__ __align__(16) unsigned short Abuf[64][136];
  const int coll = threadIdx.x & 15;
  float binv[8], boutv[8];
#pragma unroll
  for (int nt = 0; nt < 8; ++nt) {
    binv[nt] = b_in[nt * 16 + coll];
    boutv[nt] = b_out[nt * 16 + coll];
  }
  level_body<BOUNDS>(x, mask, emb, w_sw, h, out, s + blockIdx.x * 64, e, Abuf,
                     threadIdx.x, binv, boutv);
}

// Levels 2 (rows 9..72), 1 (1..8), 0 (0) in one block; __syncthreads between
// levels orders the same-block global h RAW.
__global__ __launch_bounds__(256) void tail_kernel(
    const int* __restrict__ x, const int* __restrict__ mask,
    const float* __restrict__ emb, const float* __restrict__ b_in,
    const float* __restrict__ b_out, const unsigned short* __restrict__ w_sw,
    unsigned short* __restrict__ h, float* __restrict__ out) {
  __shared__ __align__(16) unsigned short Abuf[64][136];
  const int coll = threadIdx.x & 15;
  float binv[8], boutv[8];
#pragma unroll
  for (int nt = 0; nt < 8; ++nt) {
    binv[nt] = b_in[nt * 16 + coll];
    boutv[nt] = b_out[nt * 16 + coll];
  }
  level_body<true>(x, mask, emb, w_sw, h, out, 9, 73, Abuf, threadIdx.x, binv,
                   boutv);
  __syncthreads();
  level_body<true>(x, mask, emb, w_sw, h, out, 1, 9, Abuf, threadIdx.x, binv,
                   boutv);
  __syncthreads();
  level_body<true>(x, mask, emb, w_sw, h, out, 0, 1, Abuf, threadIdx.x, binv,
                   boutv);
}

extern "C" void kernel_launch(void* const* d_in, const int* in_sizes, int n_in,
                              void* d_out, int out_size, void* d_ws,
                              size_t ws_size, hipStream_t stream) {
  const int* x = (const int*)d_in[0];
  const int* mask = (const int*)d_in[1];
  // d_in[2] = children: implied (child rows of i are i*8+1..i*8+8)
  const float* emb = (const float*)d_in[3];
  const float* W_in = (const float*)d_in[4];
  const float* b_in = (const float*)d_in[5];
  const float* U = (const float*)d_in[6];
  const float* W_out = (const float*)d_in[7];
  const float* b_out = (const float*)d_in[8];
  float* out = (float*)d_out;

  unsigned short* h = (unsigned short*)d_ws;
  unsigned short* w_sw = h + (size_t)NNODES * 128;

  prep_weights<<<192, 256, 0, stream>>>(W_in, U, W_out, w_sw);

  // leaf l=6: rows 37449..299592 (4096 tiles, 2/block)
  leaf_kernel<<<2048, 256, 0, stream>>>(x, mask, emb, b_in, b_out, w_sw, h,
                                        out);
  // l=5..3: exact x64 levels, no bounds checks
  level_kernel<false><<<512, 256, 0, stream>>>(x, mask, emb, b_in, b_out, w_sw,
                                               h, out, 4681, 37449);
  level_kernel<false><<<64, 256, 0, stream>>>(x, mask, emb, b_in, b_out, w_sw,
                                              h, out, 585, 4681);
  level_kernel<false><<<8, 256, 0, stream>>>(x, mask, emb, b_in, b_out, w_sw,
                                             h, out, 73, 585);
  // l=2,1,0 merged
  tail_kernel<<<1, 256, 0, stream>>>(x, mask, emb, b_in, b_out, w_sw, h, out);
}